// Round 11
// baseline (93.896 us; speedup 1.0000x reference)
//
#include <hip/hip_runtime.h>

// out[co*4+n, ci*4+o, y, x] = sum_{c,ky,kx} k1[co*4+n, ci*4+c, y+ky-7, x+kx-7]
//                                         * k2[co*4+o, ci*4+c, ky, kx]
// MFMA per (co,ci,c,ky):  OUT[y][x] (o=0..3) += sum_u Apad[y+ky][u] * k2[o][ky][u-x]
//   A-frag: lane(y=l&15, kg=l>>4) reads 8 contiguous bf16 (ds_read_b128)
//   B-frag: 8x ds_read_b64 from o-interleaved zero-padded Toeplitz table + v_perm.
// R11 = R9 (best: 85.6us) + 2-round epilogue (17-stride slabs, 4 barriers not 8)
//   + s_setprio(1) around the MFMA cluster (waves are phase-diverse, attn-like).
// R10 lesson: 16x ds_read_b32 direct-frag reads spilled (WRITE +32MB) and raised
//   LDS instr count; reverted to R9's 8x b64 + 16 perm form.
// 8 waves (512 thr), wave = (c = wid&3, np = wid>>2 handling n in {2np,2np+1}).
// Apad 2-D shared-pad tiling: 8 vertical bands (stride 22 rows) x 2 horizontal
//   (cols 0/24); only the discarded yl=15 output row ever reads neighbor data.
// Toeplitz tbl rows stride 32 units share zeros (window 46 < next row's data).

typedef float f32x4 __attribute__((ext_vector_type(4)));
typedef __bf16 bf16x8 __attribute__((ext_vector_type(8)));

#define KS 15
#define SP 225
#define NCH 256
#define RSTRIDE 56                    // shorts per Apad row
#define ROWS 183                      // 22*7 + 29
#define APAD_SHORTS (ROWS * RSTRIDE)  // 10248 shorts = 20496 B
#define TBL_OFF (APAD_SHORTS * 2)     // 20496 B, 16B aligned
#define TBL_UPC 496                   // table units (8B) per input channel c
#define ARENA_B (TBL_OFF + 4 * TBL_UPC * 8)   // 36368 B

__device__ __forceinline__ unsigned short f2bf(float f) {
    unsigned u = __builtin_bit_cast(unsigned, f);
    u += 0x7FFFu + ((u >> 16) & 1u);   // RNE (finite normals)
    return (unsigned short)(u >> 16);
}

__global__ __launch_bounds__(512, 6)
void blade_conv_mfma(const float* __restrict__ k1,
                     const float* __restrict__ k2,
                     float* __restrict__ out) {
    // phase 1: Apad bf16 [183 rows][56 cols] + Toeplitz tbl [4c][496 u64]
    // phase 2: slabs f32 [8 wid][4 o][16 x][17 y] = 34816 B (overlaid)
    __shared__ __align__(16) unsigned char arena[ARENA_B];
    unsigned short*     Apad  = (unsigned short*)arena;
    unsigned long long* tbl   = (unsigned long long*)(arena + TBL_OFF);
    float*              slabs = (float*)arena;

    const int tid  = threadIdx.x;
    const int lane = tid & 63;
    const int wid  = tid >> 6;            // 8 waves
    const int c_w  = wid & 3;             // input channel c
    const int np   = wid >> 2;            // n-half: n in {2np, 2np+1}
    const int co = blockIdx.x, ci = blockIdx.y;

    // ---- zero whole arena (36368/16 = 2273 f32x4) ----
    f32x4 z = {0.f, 0.f, 0.f, 0.f};
    for (int i = tid; i < ARENA_B / 16; i += 512) ((f32x4*)arena)[i] = z;
    __syncthreads();

    // ---- staging: thread (lo < 225, half) owns one (y,x) cell ----
    {
        const int lo = tid & 255, half = tid >> 8;
        if (lo < 225) {
            const int y = lo / 15, x = lo - y * 15;
            // k1: planes 8*half .. 8*half+7  (n = 2*half + j>>2, c = j&3)
            #pragma unroll
            for (int j = 0; j < 8; ++j) {
                int n = 2 * half + (j >> 2), cc = j & 3;
                float v = k1[((size_t)((co * 4 + n) * NCH + ci * 4 + cc)) * SP + lo];
                int band = n * 2 + (cc >> 1), side = cc & 1;
                Apad[(band * 22 + 7 + y) * RSTRIDE + side * 24 + 7 + x] = f2bf(v);
            }
            // k2: channels c = 2*half, 2*half+1  (ky=y, kx=x)
            #pragma unroll
            for (int jj = 0; jj < 2; ++jj) {
                int cc = 2 * half + jj;
                size_t base = ((size_t)(co * 4) * NCH + ci * 4 + cc) * SP + lo;  // o=0
                float v0 = k2[base];
                float v1 = k2[base + (size_t)NCH * SP];
                float v2 = k2[base + 2 * (size_t)NCH * SP];
                float v3 = k2[base + 3 * (size_t)NCH * SP];
                unsigned lw = (unsigned)f2bf(v0) | ((unsigned)f2bf(v1) << 16);
                unsigned hw = (unsigned)f2bf(v2) | ((unsigned)f2bf(v3) << 16);
                tbl[cc * TBL_UPC + 32 * y + x + 15] =
                    (unsigned long long)lw | ((unsigned long long)hw << 32);
            }
        }
    }
    __syncthreads();

    // ---- K loop: 15 ky chunks, K=32 (u) each ----
    f32x4 acc[2][4];
    #pragma unroll
    for (int g = 0; g < 2; ++g)
        #pragma unroll
        for (int o = 0; o < 4; ++o)
            acc[g][o] = z;

    const int yl    = lane & 15;       // output y (M); also consuming x for B
    const int kg    = lane >> 4;       // k-group
    const int side_w = c_w & 1, whalf = c_w >> 1;
    const int acol  = side_w * 24 + (kg << 3);
    const unsigned long long* tbase =
        &tbl[c_w * TBL_UPC + (kg << 3) - yl + 15];

    #pragma unroll
    for (int ky = 0; ky < 15; ++ky) {
        bf16x8 af[2];
        #pragma unroll
        for (int g = 0; g < 2; ++g) {
            int band = (2 * np + g) * 2 + whalf;
            af[g] = *(const bf16x8*)&Apad[(band * 22 + yl + ky) * RSTRIDE + acol];
        }
        unsigned long long q[8];
        #pragma unroll
        for (int j = 0; j < 8; ++j) q[j] = tbase[32 * ky + j];

        union { bf16x8 v; unsigned u[4]; } bo0, bo1, bo2, bo3;
        #pragma unroll
        for (int t = 0; t < 4; ++t) {
            unsigned a0 = (unsigned)q[2 * t],         a1 = (unsigned)q[2 * t + 1];
            unsigned b0 = (unsigned)(q[2 * t] >> 32), b1 = (unsigned)(q[2 * t + 1] >> 32);
            bo0.u[t] = __builtin_amdgcn_perm(a1, a0, 0x05040100u);
            bo1.u[t] = __builtin_amdgcn_perm(a1, a0, 0x07060302u);
            bo2.u[t] = __builtin_amdgcn_perm(b1, b0, 0x05040100u);
            bo3.u[t] = __builtin_amdgcn_perm(b1, b0, 0x07060302u);
        }
        __builtin_amdgcn_s_setprio(1);
        #pragma unroll
        for (int g = 0; g < 2; ++g) {
            acc[g][0] = __builtin_amdgcn_mfma_f32_16x16x32_bf16(af[g], bo0.v, acc[g][0], 0, 0, 0);
            acc[g][1] = __builtin_amdgcn_mfma_f32_16x16x32_bf16(af[g], bo1.v, acc[g][1], 0, 0, 0);
            acc[g][2] = __builtin_amdgcn_mfma_f32_16x16x32_bf16(af[g], bo2.v, acc[g][2], 0, 0, 0);
            acc[g][3] = __builtin_amdgcn_mfma_f32_16x16x32_bf16(af[g], bo3.v, acc[g][3], 0, 0, 0);
        }
        __builtin_amdgcn_s_setprio(0);
    }

    // ---- cross-wave (c) reduction: 2 rounds (r = n sub-index g) ----
    // slab layout: [8 wid][4 o][16 x][17 y] floats (17 coprime 32 -> no conflicts)
    const int xl = lane & 15;
    #pragma unroll
    for (int r = 0; r < 2; ++r) {
        __syncthreads();   // r=0: Apad/tbl reads done everywhere; r=1: prev readout done
        {
            float* slab = slabs + wid * 1088;   // [4 o][16 x][17 y]
            #pragma unroll
            for (int o = 0; o < 4; ++o)
                *(f32x4*)&slab[o * 272 + xl * 17 + (kg << 2)] = acc[r][o];
        }
        __syncthreads();
        for (int idx = tid; idx < 1800; idx += 512) {
            int no = idx / 225;                 // 0..7 = (npg, o)
            int rem = idx - no * 225;
            int npg = no >> 2, o = no & 3;
            int yy = rem / 15, xx = rem - yy * 15;
            int soff = o * 272 + xx * 17 + yy;
            const float* sb = slabs + npg * 4352;   // 4 waves of this np
            float s = sb[soff] + sb[1088 + soff] + sb[2176 + soff] + sb[3264 + soff];
            int n = 2 * npg + r;
            out[((size_t)((co * 4 + n) * NCH + ci * 4 + o)) * SP + rem] = s;
        }
    }
}

extern "C" void kernel_launch(void* const* d_in, const int* in_sizes, int n_in,
                              void* d_out, int out_size, void* d_ws, size_t ws_size,
                              hipStream_t stream) {
    (void)in_sizes; (void)n_in; (void)d_ws; (void)ws_size; (void)out_size;
    const float* k1 = (const float*)d_in[0];
    const float* k2 = (const float*)d_in[1];
    float* out = (float*)d_out;

    dim3 grid(64, 64, 1);
    dim3 block(512, 1, 1);
    hipLaunchKernelGGL(blade_conv_mfma, grid, block, 0, stream, k1, k2, out);
}

// Round 12
// 93.716 us; speedup vs baseline: 1.0019x; 1.0019x over previous
//
#include <hip/hip_runtime.h>

// out[co*4+n, ci*4+o, y, x] = sum_{c,ky,kx} k1[co*4+n, ci*4+c, y+ky-7, x+kx-7]
//                                         * k2[co*4+o, ci*4+c, ky, kx]
// MFMA per (co,ci,c,ky):  OUT[y][x] (o=0..3) += sum_u Apad[y+ky][u] * k2[o][ky][u-x]
//   A-frag: lane(y=l&15, kg=l>>4) reads 8 contiguous bf16 (ds_read_b128)
//   B-frag: 8x ds_read_b64 from o-interleaved zero-padded Toeplitz table + v_perm.
// R12 = R9 K-loop (proven 85.6us; NO setprio — R11 showed setprio costs ~17us in
//   this symmetric-wave loop, matching m190's GEMM-negative) + R11's improved
//   epilogue (2 rounds / 4 barriers, 17-stride slabs: coprime-32 -> <=2-way
//   conflicts vs R9's stride-20 8-way readout).
// 8 waves (512 thr), wave = (c = wid&3, np = wid>>2 handling n in {2np,2np+1}).
// Apad 2-D shared-pad tiling: 8 vertical bands (stride 22 rows) x 2 horizontal
//   (cols 0/24); only the discarded yl=15 output row ever reads neighbor data.
// Toeplitz tbl rows stride 32 units share zeros (window 46 < next row's data).

typedef float f32x4 __attribute__((ext_vector_type(4)));
typedef __bf16 bf16x8 __attribute__((ext_vector_type(8)));

#define KS 15
#define SP 225
#define NCH 256
#define RSTRIDE 56                    // shorts per Apad row
#define ROWS 183                      // 22*7 + 29
#define APAD_SHORTS (ROWS * RSTRIDE)  // 10248 shorts = 20496 B
#define TBL_OFF (APAD_SHORTS * 2)     // 20496 B, 16B aligned
#define TBL_UPC 496                   // table units (8B) per input channel c
#define ARENA_B (TBL_OFF + 4 * TBL_UPC * 8)   // 36368 B

__device__ __forceinline__ unsigned short f2bf(float f) {
    unsigned u = __builtin_bit_cast(unsigned, f);
    u += 0x7FFFu + ((u >> 16) & 1u);   // RNE (finite normals)
    return (unsigned short)(u >> 16);
}

__global__ __launch_bounds__(512, 6)
void blade_conv_mfma(const float* __restrict__ k1,
                     const float* __restrict__ k2,
                     float* __restrict__ out) {
    // phase 1: Apad bf16 [183 rows][56 cols] + Toeplitz tbl [4c][496 u64]
    // phase 2: slabs f32 [8 wid][4 o][16 x][17 y] = 34816 B (overlaid)
    __shared__ __align__(16) unsigned char arena[ARENA_B];
    unsigned short*     Apad  = (unsigned short*)arena;
    unsigned long long* tbl   = (unsigned long long*)(arena + TBL_OFF);
    float*              slabs = (float*)arena;

    const int tid  = threadIdx.x;
    const int lane = tid & 63;
    const int wid  = tid >> 6;            // 8 waves
    const int c_w  = wid & 3;             // input channel c
    const int np   = wid >> 2;            // n-half: n in {2np, 2np+1}
    const int co = blockIdx.x, ci = blockIdx.y;

    // ---- zero whole arena (36368/16 = 2273 f32x4) ----
    f32x4 z = {0.f, 0.f, 0.f, 0.f};
    for (int i = tid; i < ARENA_B / 16; i += 512) ((f32x4*)arena)[i] = z;
    __syncthreads();

    // ---- staging: thread (lo < 225, half) owns one (y,x) cell ----
    {
        const int lo = tid & 255, half = tid >> 8;
        if (lo < 225) {
            const int y = lo / 15, x = lo - y * 15;
            // k1: planes 8*half .. 8*half+7  (n = 2*half + j>>2, c = j&3)
            #pragma unroll
            for (int j = 0; j < 8; ++j) {
                int n = 2 * half + (j >> 2), cc = j & 3;
                float v = k1[((size_t)((co * 4 + n) * NCH + ci * 4 + cc)) * SP + lo];
                int band = n * 2 + (cc >> 1), side = cc & 1;
                Apad[(band * 22 + 7 + y) * RSTRIDE + side * 24 + 7 + x] = f2bf(v);
            }
            // k2: channels c = 2*half, 2*half+1  (ky=y, kx=x)
            #pragma unroll
            for (int jj = 0; jj < 2; ++jj) {
                int cc = 2 * half + jj;
                size_t base = ((size_t)(co * 4) * NCH + ci * 4 + cc) * SP + lo;  // o=0
                float v0 = k2[base];
                float v1 = k2[base + (size_t)NCH * SP];
                float v2 = k2[base + 2 * (size_t)NCH * SP];
                float v3 = k2[base + 3 * (size_t)NCH * SP];
                unsigned lw = (unsigned)f2bf(v0) | ((unsigned)f2bf(v1) << 16);
                unsigned hw = (unsigned)f2bf(v2) | ((unsigned)f2bf(v3) << 16);
                tbl[cc * TBL_UPC + 32 * y + x + 15] =
                    (unsigned long long)lw | ((unsigned long long)hw << 32);
            }
        }
    }
    __syncthreads();

    // ---- K loop: 15 ky chunks, K=32 (u) each ----
    f32x4 acc[2][4];
    #pragma unroll
    for (int g = 0; g < 2; ++g)
        #pragma unroll
        for (int o = 0; o < 4; ++o)
            acc[g][o] = z;

    const int yl    = lane & 15;       // output y (M); also consuming x for B
    const int kg    = lane >> 4;       // k-group
    const int side_w = c_w & 1, whalf = c_w >> 1;
    const int acol  = side_w * 24 + (kg << 3);
    const unsigned long long* tbase =
        &tbl[c_w * TBL_UPC + (kg << 3) - yl + 15];

    #pragma unroll
    for (int ky = 0; ky < 15; ++ky) {
        bf16x8 af[2];
        #pragma unroll
        for (int g = 0; g < 2; ++g) {
            int band = (2 * np + g) * 2 + whalf;
            af[g] = *(const bf16x8*)&Apad[(band * 22 + yl + ky) * RSTRIDE + acol];
        }
        unsigned long long q[8];
        #pragma unroll
        for (int j = 0; j < 8; ++j) q[j] = tbase[32 * ky + j];

        union { bf16x8 v; unsigned u[4]; } bo0, bo1, bo2, bo3;
        #pragma unroll
        for (int t = 0; t < 4; ++t) {
            unsigned a0 = (unsigned)q[2 * t],         a1 = (unsigned)q[2 * t + 1];
            unsigned b0 = (unsigned)(q[2 * t] >> 32), b1 = (unsigned)(q[2 * t + 1] >> 32);
            bo0.u[t] = __builtin_amdgcn_perm(a1, a0, 0x05040100u);
            bo1.u[t] = __builtin_amdgcn_perm(a1, a0, 0x07060302u);
            bo2.u[t] = __builtin_amdgcn_perm(b1, b0, 0x05040100u);
            bo3.u[t] = __builtin_amdgcn_perm(b1, b0, 0x07060302u);
        }
        #pragma unroll
        for (int g = 0; g < 2; ++g) {
            acc[g][0] = __builtin_amdgcn_mfma_f32_16x16x32_bf16(af[g], bo0.v, acc[g][0], 0, 0, 0);
            acc[g][1] = __builtin_amdgcn_mfma_f32_16x16x32_bf16(af[g], bo1.v, acc[g][1], 0, 0, 0);
            acc[g][2] = __builtin_amdgcn_mfma_f32_16x16x32_bf16(af[g], bo2.v, acc[g][2], 0, 0, 0);
            acc[g][3] = __builtin_amdgcn_mfma_f32_16x16x32_bf16(af[g], bo3.v, acc[g][3], 0, 0, 0);
        }
    }

    // ---- cross-wave (c) reduction: 2 rounds (r = n sub-index g) ----
    // slab layout: [8 wid][4 o][16 x][17 y] floats (17 coprime 32 -> no conflicts)
    const int xl = lane & 15;
    #pragma unroll
    for (int r = 0; r < 2; ++r) {
        __syncthreads();   // r=0: Apad/tbl reads done everywhere; r=1: prev readout done
        {
            float* slab = slabs + wid * 1088;   // [4 o][16 x][17 y]
            #pragma unroll
            for (int o = 0; o < 4; ++o)
                *(f32x4*)&slab[o * 272 + xl * 17 + (kg << 2)] = acc[r][o];
        }
        __syncthreads();
        for (int idx = tid; idx < 1800; idx += 512) {
            int no = idx / 225;                 // 0..7 = (npg, o)
            int rem = idx - no * 225;
            int npg = no >> 2, o = no & 3;
            int yy = rem / 15, xx = rem - yy * 15;
            int soff = o * 272 + xx * 17 + yy;
            const float* sb = slabs + npg * 4352;   // 4 waves of this np
            float s = sb[soff] + sb[1088 + soff] + sb[2176 + soff] + sb[3264 + soff];
            int n = 2 * npg + r;
            out[((size_t)((co * 4 + n) * NCH + ci * 4 + o)) * SP + rem] = s;
        }
    }
}

extern "C" void kernel_launch(void* const* d_in, const int* in_sizes, int n_in,
                              void* d_out, int out_size, void* d_ws, size_t ws_size,
                              hipStream_t stream) {
    (void)in_sizes; (void)n_in; (void)d_ws; (void)ws_size; (void)out_size;
    const float* k1 = (const float*)d_in[0];
    const float* k2 = (const float*)d_in[1];
    float* out = (float*)d_out;

    dim3 grid(64, 64, 1);
    dim3 block(512, 1, 1);
    hipLaunchKernelGGL(blade_conv_mfma, grid, block, 0, stream, k1, k2, out);
}